// Round 5
// baseline (750.820 us; speedup 1.0000x reference)
//
#include <hip/hip_runtime.h>
#include <hip/hip_cooperative_groups.h>
#include <stdint.h>

namespace cg = cooperative_groups;

// ---------------------------------------------------------------------------
// Speaker pairwise loss, single cooperative kernel (eliminates ~60us of
// inter-kernel gaps). sim = F·F^T symmetric: only 128x128 tiles J>=I (2080).
// Phases (grid.sync between): convert fp32->bf16 | pass1 tiles -> partials |
// reduce1 -> thresholds | pass2 tiles -> partials | reduce2 -> sums | finalize.
// No atomics anywhere. BK=64 staging via global_load_lds w=16, XOR swizzle
// (measured 0 bank conflicts in R2/R3; the R4 BK=128 variant aliased 8-way).
// LDS ~36KB -> 4 blocks/CU; __launch_bounds__(256,4) guarantees coop capacity.
// ws: fb bf16[B*D] | pm0[2080*256] | pm1[2080*256] | tmn[B] tmx[B] psum[B] nsum[B]
// ---------------------------------------------------------------------------

typedef __attribute__((ext_vector_type(8))) short short8;   // 8 bf16
typedef __attribute__((ext_vector_type(4))) float floatx4;  // MFMA C/D

constexpr int D = 256;
constexpr int BM = 128;
constexpr int NT = 64;                    // 8192/128
constexpr int NBLK = NT * (NT + 1) / 2;   // 2080

__device__ __forceinline__ int triBase(int I) { return I * (129 - I) / 2; }

__device__ __forceinline__ unsigned f2bf(float f) {  // fp32 -> bf16, RNE
  unsigned u = __float_as_uint(f);
  return (u + 0x7FFFu + ((u >> 16) & 1u)) >> 16;
}

__device__ __forceinline__ void gl_lds16(const void* g, void* l) {
  __builtin_amdgcn_global_load_lds(
      (const __attribute__((address_space(1))) unsigned int*)g,
      (__attribute__((address_space(3))) unsigned int*)l, 16, 0, 0);
}

// ---- one 128x128 triangular tile: MFMA + fused epilogue -> 256 partials ----
template <int PASS>
__device__ __forceinline__ void do_tile(
    int t, const unsigned short* fb, const int* labels,
    const float* tmn, const float* tmx, float* pm0, float* pm1,
    short* As, short* Bs, int* labA, int* labB,
    float* tA0, float* tA1, float* tB0, float* tB1) {
  const int tid  = threadIdx.x;
  const int lane = tid & 63;
  const int wave = tid >> 6;
  const int l15  = lane & 15;
  const int quad = lane >> 4;
  const int wr   = (wave >> 1) * 64;
  const int wc   = (wave & 1) * 64;

  // triangular decode
  int I = (int)((129.0f - sqrtf(16641.0f - 8.0f * (float)t)) * 0.5f);
  while (I * (129 - I) / 2 > t) --I;
  while ((I + 1) * (129 - (I + 1)) / 2 <= t) ++I;
  const int J = I + (t - triBase(I));
  const bool diag = (I == J);
  const int row0 = I * BM, col0 = J * BM;

  const float ONE_EPS = 1.0f - 1e-5f;
  const float INF = __builtin_inff();

  __syncthreads();   // protect smem reuse (prev tile scratch / phase)
  if (tid < BM) {
    labA[tid] = labels[row0 + tid];
    labB[tid] = labels[col0 + tid];
    if (PASS == 2) {
      tA0[tid] = tmn[row0 + tid];
      tA1[tid] = tmx[row0 + tid];
      tB0[tid] = tmn[col0 + tid];
      tB1[tid] = tmx[col0 + tid];
    }
  }

  const int srow = (wave << 5) + (lane >> 3);
  const int slot = lane & 7;

  int arow[4], brow[4];
#pragma unroll
  for (int i = 0; i < 4; ++i) {
    arow[i] = wr + i * 16 + l15;
    brow[i] = wc + i * 16 + l15;
  }

  floatx4 acc[4][4];
#pragma unroll
  for (int rf = 0; rf < 4; ++rf)
#pragma unroll
    for (int cf = 0; cf < 4; ++cf)
      acc[rf][cf] = (floatx4)(0.f);

  // K loop: 4 chunks of 64 (BK=64 swizzle: 0 bank conflicts, measured)
  for (int kc = 0; kc < 4; ++kc) {
#pragma unroll
    for (int j = 0; j < 4; ++j) {
      int r = srow + 8 * j;
      int sw = (slot ^ (r & 7)) << 4;
      const char* ga = (const char*)fb + (((size_t)(row0 + r)) << 9) + (kc << 7) + sw;
      const char* gb = (const char*)fb + (((size_t)(col0 + r)) << 9) + (kc << 7) + sw;
      gl_lds16(ga, (char*)As + (r << 7) + (slot << 4));
      gl_lds16(gb, (char*)Bs + (r << 7) + (slot << 4));
    }
    __syncthreads();
#pragma unroll
    for (int ks = 0; ks < 2; ++ks) {
      const int g = ks * 4 + quad;
      short8 a[4], b[4];
#pragma unroll
      for (int rf = 0; rf < 4; ++rf)
        a[rf] = *(const short8*)(As + arow[rf] * 64 + ((g ^ (arow[rf] & 7)) << 3));
#pragma unroll
      for (int cf = 0; cf < 4; ++cf)
        b[cf] = *(const short8*)(Bs + brow[cf] * 64 + ((g ^ (brow[cf] & 7)) << 3));
#pragma unroll
      for (int rf = 0; rf < 4; ++rf)
#pragma unroll
        for (int cf = 0; cf < 4; ++cf)
          acc[rf][cf] = __builtin_amdgcn_mfma_f32_16x16x32_bf16(a[rf], b[cf], acc[rf][cf], 0, 0, 0);
    }
    __syncthreads();
  }

  // per-lane stats
  int labc[4];
  float tBn[4], tBx[4];
#pragma unroll
  for (int cf = 0; cf < 4; ++cf) {
    labc[cf] = labB[wc + cf * 16 + l15];
    if (PASS == 2) { tBn[cf] = tB0[wc + cf * 16 + l15]; tBx[cf] = tB1[wc + cf * 16 + l15]; }
  }

  float s0[16], s1[16], c0[4], c1[4];
#pragma unroll
  for (int i = 0; i < 16; ++i) {
    s0[i] = (PASS == 1) ? INF : 0.f;
    s1[i] = (PASS == 1) ? -INF : 0.f;
  }
#pragma unroll
  for (int i = 0; i < 4; ++i) {
    c0[i] = (PASS == 1) ? INF : 0.f;
    c1[i] = (PASS == 1) ? -INF : 0.f;
  }

#pragma unroll
  for (int rf = 0; rf < 4; ++rf) {
#pragma unroll
    for (int r = 0; r < 4; ++r) {
      const int ri = wr + rf * 16 + quad * 4 + r;
      const int lr = labA[ri];
      float tRn = 0.f, tRx = 0.f;
      if (PASS == 2) { tRn = tA0[ri]; tRx = tA1[ri]; }
#pragma unroll
      for (int cf = 0; cf < 4; ++cf) {
        float sim = acc[rf][cf][r];
        bool same = (lr == labc[cf]);
        bool posok = same && (sim < ONE_EPS);
        if (PASS == 1) {
          float pc = posok ? sim : INF;
          float nc = same ? -INF : sim;
          s0[rf * 4 + r] = fminf(s0[rf * 4 + r], pc);
          s1[rf * 4 + r] = fmaxf(s1[rf * 4 + r], nc);
          c0[cf] = fminf(c0[cf], pc);
          c1[cf] = fmaxf(c1[cf], nc);
        } else {
          if (posok) {
            float e = __expf(fmaf(-2.f, sim, 1.f));
            if (sim < tRx)      s0[rf * 4 + r] += e;
            if (sim < tBx[cf])  c0[cf] += e;
          } else if (!same) {
            float e = (sim > 0.22f) ? __expf(fmaf(50.f, sim, -25.f)) : 0.f;
            if (sim > tRn)      s1[rf * 4 + r] += 1e-30f + e;
            if (sim > tBn[cf])  c1[cf] += 1e-30f + e;
          }
        }
      }
    }
  }

  // shuffle reductions: rows over l15, cols over quads
#pragma unroll
  for (int i = 0; i < 16; ++i) {
#pragma unroll
    for (int m = 1; m < 16; m <<= 1) {
      float v = __shfl_xor(s0[i], m), w = __shfl_xor(s1[i], m);
      s0[i] = (PASS == 1) ? fminf(s0[i], v) : (s0[i] + v);
      s1[i] = (PASS == 1) ? fmaxf(s1[i], w) : (s1[i] + w);
    }
  }
#pragma unroll
  for (int i = 0; i < 4; ++i) {
#pragma unroll
    for (int m = 16; m < 64; m <<= 1) {
      float v = __shfl_xor(c0[i], m), w = __shfl_xor(c1[i], m);
      c0[i] = (PASS == 1) ? fminf(c0[i], v) : (c0[i] + v);
      c1[i] = (PASS == 1) ? fmaxf(c1[i], w) : (c1[i] + w);
    }
  }

  // cross-wave combine via LDS scratch (aliases As), then plain stores
  float* sc = (float*)As;
  float* rA = sc;
  float* rB = sc + 128;
  float* cA = sc + 256;
  float* cB = sc + 384;
  __syncthreads();   // all ds_reads of As done before aliasing

  if (wc == 64 && l15 == 0) {
#pragma unroll
    for (int rf = 0; rf < 4; ++rf)
#pragma unroll
      for (int r = 0; r < 4; ++r) {
        int ri = wr + rf * 16 + quad * 4 + r;
        rA[ri] = s0[rf * 4 + r];
        rB[ri] = s1[rf * 4 + r];
      }
  }
  if (wr == 64 && quad == 0) {
#pragma unroll
    for (int cf = 0; cf < 4; ++cf) {
      int ci = wc + cf * 16 + l15;
      cA[ci] = c0[cf];
      cB[ci] = c1[cf];
    }
  }
  __syncthreads();

  if (wc == 0 && l15 == 0) {
#pragma unroll
    for (int rf = 0; rf < 4; ++rf)
#pragma unroll
      for (int r = 0; r < 4; ++r) {
        int ri = wr + rf * 16 + quad * 4 + r;
        float v = s0[rf * 4 + r], w = s1[rf * 4 + r];
        v = (PASS == 1) ? fminf(v, rA[ri]) : (v + rA[ri]);
        w = (PASS == 1) ? fmaxf(w, rB[ri]) : (w + rB[ri]);
        pm0[(size_t)t * 256 + ri] = v;
        pm1[(size_t)t * 256 + ri] = w;
      }
  }
  if (wr == 0 && quad == 0) {
#pragma unroll
    for (int cf = 0; cf < 4; ++cf) {
      int ci = wc + cf * 16 + l15;
      float v = c0[cf], w = c1[cf];
      v = (PASS == 1) ? fminf(v, cA[ci]) : (v + cA[ci]);
      w = (PASS == 1) ? fmaxf(w, cB[ci]) : (w + cB[ci]);
      if (diag) { v = (PASS == 1) ? INF : 0.f; w = (PASS == 1) ? -INF : 0.f; }
      pm0[(size_t)t * 256 + 128 + ci] = v;
      pm1[(size_t)t * 256 + 128 + ci] = w;
    }
  }
}

// ---- fold 64 partials per row (blocks 0..63 only) ----
template <int PASS>
__device__ __forceinline__ void do_reduce(const float* pm0, const float* pm1,
                                          float* o0, float* o1, float* red) {
  const int T = blockIdx.x;
  const int q = threadIdx.x & 127;
  const int h = threadIdx.x >> 7;
  const int nr = 64 - T;
  float a = (PASS == 1) ? __builtin_inff() : 0.f;
  float b = (PASS == 1) ? -__builtin_inff() : 0.f;
#pragma unroll 4
  for (int j = 0; j < 32; ++j) {
    int p = h * 32 + j;
    int t, slot;
    if (p < nr) { t = triBase(T) + p; slot = q; }
    else        { int Iq = p - nr; t = triBase(Iq) + (T - Iq); slot = 128 + q; }
    float v0 = pm0[(size_t)t * 256 + slot];
    float v1 = pm1[(size_t)t * 256 + slot];
    a = (PASS == 1) ? fminf(a, v0) : (a + v0);
    b = (PASS == 1) ? fmaxf(b, v1) : (b + v1);
  }
  if (h == 1) { red[q] = a; red[128 + q] = b; }
  __syncthreads();
  if (h == 0) {
    a = (PASS == 1) ? fminf(a, red[q]) : (a + red[q]);
    b = (PASS == 1) ? fmaxf(b, red[128 + q]) : (b + red[128 + q]);
    if (PASS == 1) { o0[T * 128 + q] = a - 0.1f; o1[T * 128 + q] = b + 0.1f; }
    else           { o0[T * 128 + q] = a;        o1[T * 128 + q] = b; }
  }
  __syncthreads();
}

__global__ __launch_bounds__(256, 4)
void mega_kernel(const float* feats, const int* labels, unsigned short* fb,
                 float* pm0, float* pm1, float* tmn, float* tmx,
                 float* psum, float* nsum, float* out) {
  __shared__ __align__(16) short As[BM * 64];   // 16KB
  __shared__ __align__(16) short Bs[BM * 64];   // 16KB
  __shared__ int   labA[BM], labB[BM];
  __shared__ float tA0[BM], tA1[BM], tB0[BM], tB1[BM];

  cg::grid_group grid = cg::this_grid();
  const int bid = blockIdx.x;
  const int nblk = gridDim.x;
  const int tid = threadIdx.x;

  // ---- phase 0: convert fp32 -> bf16 ----
  const int n4 = 8192 * D / 4;
  for (int i = bid * 256 + tid; i < n4; i += nblk * 256) {
    float4 v = ((const float4*)feats)[i];
    unsigned lo = f2bf(v.x) | (f2bf(v.y) << 16);
    unsigned hi = f2bf(v.z) | (f2bf(v.w) << 16);
    ((uint2*)fb)[i] = make_uint2(lo, hi);
  }
  __threadfence();
  grid.sync();

  // ---- phase 1: pass1 tiles ----
  for (int t = bid; t < NBLK; t += nblk)
    do_tile<1>(t, fb, labels, nullptr, nullptr, pm0, pm1,
               As, Bs, labA, labB, tA0, tA1, tB0, tB1);
  __threadfence();
  grid.sync();

  // ---- phase 2: reduce1 -> thresholds ----
  if (bid < NT) do_reduce<1>(pm0, pm1, tmn, tmx, (float*)As);
  __threadfence();
  grid.sync();

  // ---- phase 3: pass2 tiles ----
  for (int t = bid; t < NBLK; t += nblk)
    do_tile<2>(t, fb, labels, tmn, tmx, pm0, pm1,
               As, Bs, labA, labB, tA0, tA1, tB0, tB1);
  __threadfence();
  grid.sync();

  // ---- phase 4: reduce2 -> sums ----
  if (bid < NT) do_reduce<2>(pm0, pm1, psum, nsum, (float*)As);
  __threadfence();
  grid.sync();

  // ---- phase 5: finalize (block 0) ----
  if (bid == 0) {
    float* red = (float*)As;
    float loss = 0.f, cnt = 0.f;
    for (int i = tid; i < 8192; i += 256) {
      float p = psum[i], n = nsum[i];
      if (p > 0.f && n > 0.f) {
        loss += 0.5f * log1pf(p) + 0.02f * log1pf(n);
        cnt += 1.f;
      }
    }
#pragma unroll
    for (int m = 1; m < 64; m <<= 1) {
      loss += __shfl_xor(loss, m);
      cnt  += __shfl_xor(cnt, m);
    }
    int wave = tid >> 6, lane = tid & 63;
    if (lane == 0) { red[wave] = loss; red[4 + wave] = cnt; }
    __syncthreads();
    if (tid == 0) {
      float L = red[0] + red[1] + red[2] + red[3];
      float C = red[4] + red[5] + red[6] + red[7];
      out[0] = L / 8192.0f;
      out[1] = 1.0f - C / 8192.0f;
    }
  }
}

extern "C" void kernel_launch(void* const* d_in, const int* in_sizes, int n_in,
                              void* d_out, int out_size, void* d_ws, size_t ws_size,
                              hipStream_t stream) {
  const float* feats  = (const float*)d_in[0];
  const int*   labels = (const int*)d_in[1];
  const int Bn = in_sizes[1];          // 8192
  float* out = (float*)d_out;

  unsigned short* fb = (unsigned short*)d_ws;                       // 4 MB
  float* pm0  = (float*)((char*)d_ws + (size_t)Bn * D * 2);
  float* pm1  = pm0 + (size_t)NBLK * 256;
  float* tmn  = pm1 + (size_t)NBLK * 256;
  float* tmx  = tmn + Bn;
  float* psum = tmx + Bn;
  float* nsum = psum + Bn;

  int maxb = 1;
  hipOccupancyMaxActiveBlocksPerMultiprocessor(&maxb, mega_kernel, 256, 0);
  int grid = maxb * 256;               // 256 CUs
  if (grid > 1024) grid = 1024;        // 2080 tiles / >=2 per block
  if (grid < NT) grid = NT;            // reduce phases need 64 blocks

  void* args[] = {(void*)&feats, (void*)&labels, (void*)&fb, (void*)&pm0, (void*)&pm1,
                  (void*)&tmn, (void*)&tmx, (void*)&psum, (void*)&nsum, (void*)&out};
  hipLaunchCooperativeKernel(mega_kernel, dim3(grid), dim3(256), args, 0, stream);
}

// Round 6
// 208.540 us; speedup vs baseline: 3.6004x; 3.6004x over previous
//
#include <hip/hip_runtime.h>
#include <stdint.h>

// ---------------------------------------------------------------------------
// Speaker pairwise loss. sim = F·F^T symmetric: only 128x128 tiles J>=I (2080).
// Multi-kernel (R4 structure, best so far) with two fixes:
//  - BK=64 XOR swizzle (0 bank conflicts, measured R2/R3; R4's BK=128 aliased)
//  - double-buffered LDS K-loop: stage chunk kc+1 after the barrier, before
//    MFMA on kc -> load latency overlaps compute (kernel is latency-bound,
//    MfmaUtil 9%). LDS 67KB -> 2 blocks/CU (same as R4).
// NO atomics: per-tile partials via plain stores; reduce kernels fold them.
// NO forced min-waves launch bound (R5: (256,4) -> VGPR 64 -> acc spilled ->
// 226MB scratch traffic, 751us. Never cap below the 64-reg accumulator.)
// ws: fb bf16[B*D] | pm0[2080*256] | pm1[2080*256] | tmn[B] tmx[B] psum[B] nsum[B]
// ---------------------------------------------------------------------------

typedef __attribute__((ext_vector_type(8))) short short8;   // 8 bf16
typedef __attribute__((ext_vector_type(4))) float floatx4;  // MFMA C/D

constexpr int D = 256;
constexpr int BM = 128;
constexpr int NT = 64;                    // 8192/128
constexpr int NBLK = NT * (NT + 1) / 2;   // 2080

__device__ __forceinline__ int triBase(int I) { return I * (129 - I) / 2; }

__device__ __forceinline__ unsigned f2bf(float f) {  // fp32 -> bf16, RNE
  unsigned u = __float_as_uint(f);
  return (u + 0x7FFFu + ((u >> 16) & 1u)) >> 16;
}

__device__ __forceinline__ void gl_lds16(const void* g, void* l) {
  __builtin_amdgcn_global_load_lds(
      (const __attribute__((address_space(1))) unsigned int*)g,
      (__attribute__((address_space(3))) unsigned int*)l, 16, 0, 0);
}

__global__ void convert_kernel(const float* __restrict__ feats,
                               unsigned short* __restrict__ fb, int n4) {
  int i = blockIdx.x * blockDim.x + threadIdx.x;
  if (i < n4) {
    float4 v = ((const float4*)feats)[i];
    unsigned lo = f2bf(v.x) | (f2bf(v.y) << 16);
    unsigned hi = f2bf(v.z) | (f2bf(v.w) << 16);
    ((uint2*)fb)[i] = make_uint2(lo, hi);
  }
}

template <int PASS>
__global__ __launch_bounds__(256)
void pair_kernel(const unsigned short* __restrict__ fb, const int* __restrict__ labels,
                 const float* __restrict__ tmn, const float* __restrict__ tmx,
                 float* __restrict__ pm0, float* __restrict__ pm1) {
  // double-buffered BK=64 tiles: buf0 As|Bs, buf1 As|Bs (16KB each, 64KB total)
  __shared__ __align__(16) short Abuf[2][BM * 64];
  __shared__ __align__(16) short Bbuf[2][BM * 64];
  __shared__ int   labA[BM], labB[BM];
  __shared__ float tA0[BM], tA1[BM], tB0[BM], tB1[BM];

  // ---- triangular decode ----
  const int t = blockIdx.x;
  int I = (int)((129.0f - sqrtf(16641.0f - 8.0f * (float)t)) * 0.5f);
  while (I * (129 - I) / 2 > t) --I;
  while ((I + 1) * (129 - (I + 1)) / 2 <= t) ++I;
  const int J = I + (t - triBase(I));
  const bool diag = (I == J);
  const int row0 = I * BM, col0 = J * BM;

  const int tid  = threadIdx.x;
  const int lane = tid & 63;
  const int wave = tid >> 6;
  const int l15  = lane & 15;
  const int quad = lane >> 4;
  const int wr   = (wave >> 1) * 64;
  const int wc   = (wave & 1) * 64;

  const float ONE_EPS = 1.0f - 1e-5f;
  const float INF = __builtin_inff();

  // staging geometry (BK=64): wave covers 32 rows, 8 lanes/row, 16B/lane
  const int srow = (wave << 5) + (lane >> 3);
  const int slot = lane & 7;

  // issue chunk-kc loads into buffer bf
  auto stage = [&](int kc, int bf) {
#pragma unroll
    for (int j = 0; j < 4; ++j) {
      int r = srow + 8 * j;
      int sw = (slot ^ (r & 7)) << 4;     // XOR swizzle (0 conflicts, measured)
      const char* ga = (const char*)fb + (((size_t)(row0 + r)) << 9) + (kc << 7) + sw;
      const char* gb = (const char*)fb + (((size_t)(col0 + r)) << 9) + (kc << 7) + sw;
      gl_lds16(ga, (char*)Abuf[bf] + (r << 7) + (slot << 4));
      gl_lds16(gb, (char*)Bbuf[bf] + (r << 7) + (slot << 4));
    }
  };

  stage(0, 0);                            // prologue: chunk 0 -> buf 0

  if (tid < BM) {
    labA[tid] = labels[row0 + tid];
    labB[tid] = labels[col0 + tid];
    if (PASS == 2) {
      tA0[tid] = tmn[row0 + tid];
      tA1[tid] = tmx[row0 + tid];
      tB0[tid] = tmn[col0 + tid];
      tB1[tid] = tmx[col0 + tid];
    }
  }

  int arow[4], brow[4];
#pragma unroll
  for (int i = 0; i < 4; ++i) {
    arow[i] = wr + i * 16 + l15;
    brow[i] = wc + i * 16 + l15;
  }

  floatx4 acc[4][4];
#pragma unroll
  for (int rf = 0; rf < 4; ++rf)
#pragma unroll
    for (int cf = 0; cf < 4; ++cf)
      acc[rf][cf] = (floatx4)(0.f);

  __syncthreads();                        // buf0 ready

  // ---- pipelined K loop: 4 chunks of 64 ----
  int bf = 0;
#pragma unroll
  for (int kc = 0; kc < 4; ++kc) {
    if (kc < 3) stage(kc + 1, bf ^ 1);    // overlap next-chunk loads with MFMA
    const short* As = Abuf[bf];
    const short* Bs = Bbuf[bf];
#pragma unroll
    for (int ks = 0; ks < 2; ++ks) {
      const int g = ks * 4 + quad;
      short8 a[4], b[4];
#pragma unroll
      for (int rf = 0; rf < 4; ++rf)
        a[rf] = *(const short8*)(As + arow[rf] * 64 + ((g ^ (arow[rf] & 7)) << 3));
#pragma unroll
      for (int cf = 0; cf < 4; ++cf)
        b[cf] = *(const short8*)(Bs + brow[cf] * 64 + ((g ^ (brow[cf] & 7)) << 3));
#pragma unroll
      for (int rf = 0; rf < 4; ++rf)
#pragma unroll
        for (int cf = 0; cf < 4; ++cf)
          acc[rf][cf] = __builtin_amdgcn_mfma_f32_16x16x32_bf16(a[rf], b[cf], acc[rf][cf], 0, 0, 0);
    }
    __syncthreads();                      // drains (overlapped) kc+1 loads
    bf ^= 1;
  }

  // ---- per-lane stats ----
  int labc[4];
  float tBn[4], tBx[4];
#pragma unroll
  for (int cf = 0; cf < 4; ++cf) {
    labc[cf] = labB[wc + cf * 16 + l15];
    if (PASS == 2) { tBn[cf] = tB0[wc + cf * 16 + l15]; tBx[cf] = tB1[wc + cf * 16 + l15]; }
  }

  float s0[16], s1[16], c0[4], c1[4];
#pragma unroll
  for (int i = 0; i < 16; ++i) {
    s0[i] = (PASS == 1) ? INF : 0.f;
    s1[i] = (PASS == 1) ? -INF : 0.f;
  }
#pragma unroll
  for (int i = 0; i < 4; ++i) {
    c0[i] = (PASS == 1) ? INF : 0.f;
    c1[i] = (PASS == 1) ? -INF : 0.f;
  }

#pragma unroll
  for (int rf = 0; rf < 4; ++rf) {
#pragma unroll
    for (int r = 0; r < 4; ++r) {
      const int ri = wr + rf * 16 + quad * 4 + r;
      const int lr = labA[ri];
      float tRn = 0.f, tRx = 0.f;
      if (PASS == 2) { tRn = tA0[ri]; tRx = tA1[ri]; }
#pragma unroll
      for (int cf = 0; cf < 4; ++cf) {
        float sim = acc[rf][cf][r];
        bool same = (lr == labc[cf]);
        bool posok = same && (sim < ONE_EPS);
        if (PASS == 1) {
          float pc = posok ? sim : INF;
          float nc = same ? -INF : sim;
          s0[rf * 4 + r] = fminf(s0[rf * 4 + r], pc);
          s1[rf * 4 + r] = fmaxf(s1[rf * 4 + r], nc);
          c0[cf] = fminf(c0[cf], pc);
          c1[cf] = fmaxf(c1[cf], nc);
        } else {
          if (posok) {
            float e = __expf(fmaf(-2.f, sim, 1.f));
            if (sim < tRx)      s0[rf * 4 + r] += e;
            if (sim < tBx[cf])  c0[cf] += e;
          } else if (!same) {
            float e = (sim > 0.22f) ? __expf(fmaf(50.f, sim, -25.f)) : 0.f;
            if (sim > tRn)      s1[rf * 4 + r] += 1e-30f + e;
            if (sim > tBn[cf])  c1[cf] += 1e-30f + e;
          }
        }
      }
    }
  }

  // ---- shuffle reductions: rows over l15, cols over quads ----
#pragma unroll
  for (int i = 0; i < 16; ++i) {
#pragma unroll
    for (int m = 1; m < 16; m <<= 1) {
      float v = __shfl_xor(s0[i], m), w = __shfl_xor(s1[i], m);
      s0[i] = (PASS == 1) ? fminf(s0[i], v) : (s0[i] + v);
      s1[i] = (PASS == 1) ? fmaxf(s1[i], w) : (s1[i] + w);
    }
  }
#pragma unroll
  for (int i = 0; i < 4; ++i) {
#pragma unroll
    for (int m = 16; m < 64; m <<= 1) {
      float v = __shfl_xor(c0[i], m), w = __shfl_xor(c1[i], m);
      c0[i] = (PASS == 1) ? fminf(c0[i], v) : (c0[i] + v);
      c1[i] = (PASS == 1) ? fmaxf(c1[i], w) : (c1[i] + w);
    }
  }

  // ---- cross-wave combine via LDS scratch (aliases Abuf[0]), plain stores ----
  float* sc = (float*)Abuf[0];
  float* rA = sc;
  float* rB = sc + 128;
  float* cA = sc + 256;
  float* cB = sc + 384;
  __syncthreads();   // all ds_reads of Abuf done before aliasing

  if (wc == 64 && l15 == 0) {
#pragma unroll
    for (int rf = 0; rf < 4; ++rf)
#pragma unroll
      for (int r = 0; r < 4; ++r) {
        int ri = wr + rf * 16 + quad * 4 + r;
        rA[ri] = s0[rf * 4 + r];
        rB[ri] = s1[rf * 4 + r];
      }
  }
  if (wr == 64 && quad == 0) {
#pragma unroll
    for (int cf = 0; cf < 4; ++cf) {
      int ci = wc + cf * 16 + l15;
      cA[ci] = c0[cf];
      cB[ci] = c1[cf];
    }
  }
  __syncthreads();

  if (wc == 0 && l15 == 0) {
#pragma unroll
    for (int rf = 0; rf < 4; ++rf)
#pragma unroll
      for (int r = 0; r < 4; ++r) {
        int ri = wr + rf * 16 + quad * 4 + r;
        float v = s0[rf * 4 + r], w = s1[rf * 4 + r];
        v = (PASS == 1) ? fminf(v, rA[ri]) : (v + rA[ri]);
        w = (PASS == 1) ? fmaxf(w, rB[ri]) : (w + rB[ri]);
        pm0[(size_t)t * 256 + ri] = v;
        pm1[(size_t)t * 256 + ri] = w;
      }
  }
  if (wr == 0 && quad == 0) {
#pragma unroll
    for (int cf = 0; cf < 4; ++cf) {
      int ci = wc + cf * 16 + l15;
      float v = c0[cf], w = c1[cf];
      v = (PASS == 1) ? fminf(v, cA[ci]) : (v + cA[ci]);
      w = (PASS == 1) ? fmaxf(w, cB[ci]) : (w + cB[ci]);
      if (diag) { v = (PASS == 1) ? INF : 0.f; w = (PASS == 1) ? -INF : 0.f; }
      pm0[(size_t)t * 256 + 128 + ci] = v;
      pm1[(size_t)t * 256 + 128 + ci] = w;
    }
  }
}

// fold 64 partials per row -> thresholds (pass1 output)
__global__ void reduce1_kernel(const float* __restrict__ pm0, const float* __restrict__ pm1,
                               float* __restrict__ tmn, float* __restrict__ tmx) {
  __shared__ float smn[128], smx[128];
  const int T = blockIdx.x;            // 64 blocks
  const int q = threadIdx.x & 127;
  const int h = threadIdx.x >> 7;
  const int nr = 64 - T;
  float mn = __builtin_inff(), mx = -__builtin_inff();
#pragma unroll 4
  for (int j = 0; j < 32; ++j) {
    int p = h * 32 + j;
    int t, slot;
    if (p < nr) { t = triBase(T) + p; slot = q; }
    else        { int Iq = p - nr; t = triBase(Iq) + (T - Iq); slot = 128 + q; }
    mn = fminf(mn, pm0[(size_t)t * 256 + slot]);
    mx = fmaxf(mx, pm1[(size_t)t * 256 + slot]);
  }
  if (h == 1) { smn[q] = mn; smx[q] = mx; }
  __syncthreads();
  if (h == 0) {
    mn = fminf(mn, smn[q]);
    mx = fmaxf(mx, smx[q]);
    tmn[T * 128 + q] = mn - 0.1f;   // min_pos - MARGIN (inf-safe)
    tmx[T * 128 + q] = mx + 0.1f;   // max_neg + MARGIN
  }
}

// fold 64 partials per row -> pos/neg sums (pass2 output)
__global__ void reduce2_kernel(const float* __restrict__ pm0, const float* __restrict__ pm1,
                               float* __restrict__ psum, float* __restrict__ nsum) {
  __shared__ float sp[128], sn[128];
  const int T = blockIdx.x;
  const int q = threadIdx.x & 127;
  const int h = threadIdx.x >> 7;
  const int nr = 64 - T;
  float p = 0.f, n = 0.f;
#pragma unroll 4
  for (int j = 0; j < 32; ++j) {
    int pp = h * 32 + j;
    int t, slot;
    if (pp < nr) { t = triBase(T) + pp; slot = q; }
    else         { int Iq = pp - nr; t = triBase(Iq) + (T - Iq); slot = 128 + q; }
    p += pm0[(size_t)t * 256 + slot];
    n += pm1[(size_t)t * 256 + slot];
  }
  if (h == 1) { sp[q] = p; sn[q] = n; }
  __syncthreads();
  if (h == 0) {
    psum[T * 128 + q] = p + sp[q];
    nsum[T * 128 + q] = n + sn[q];
  }
}

__global__ void finalize_kernel(const float* __restrict__ psum, const float* __restrict__ nsum,
                                float* __restrict__ out, int Bn) {
  __shared__ float sl[4], sc2[4];
  float loss = 0.f, cnt = 0.f;
  for (int i = threadIdx.x; i < Bn; i += 256) {
    float p = psum[i], n = nsum[i];
    if (p > 0.f && n > 0.f) {
      loss += 0.5f * log1pf(p) + 0.02f * log1pf(n);
      cnt += 1.f;
    }
  }
#pragma unroll
  for (int m = 1; m < 64; m <<= 1) {
    loss += __shfl_xor(loss, m);
    cnt  += __shfl_xor(cnt, m);
  }
  int wave = threadIdx.x >> 6, lane = threadIdx.x & 63;
  if (lane == 0) { sl[wave] = loss; sc2[wave] = cnt; }
  __syncthreads();
  if (threadIdx.x == 0) {
    float L = sl[0] + sl[1] + sl[2] + sl[3];
    float C = sc2[0] + sc2[1] + sc2[2] + sc2[3];
    out[0] = L / (float)Bn;
    out[1] = 1.0f - C / (float)Bn;
  }
}

extern "C" void kernel_launch(void* const* d_in, const int* in_sizes, int n_in,
                              void* d_out, int out_size, void* d_ws, size_t ws_size,
                              hipStream_t stream) {
  const float* feats  = (const float*)d_in[0];
  const int*   labels = (const int*)d_in[1];
  const int Bn = in_sizes[1];          // 8192
  float* out = (float*)d_out;

  unsigned short* fb = (unsigned short*)d_ws;                       // 4 MB
  float* pm0  = (float*)((char*)d_ws + (size_t)Bn * D * 2);
  float* pm1  = pm0 + (size_t)NBLK * 256;
  float* tmn  = pm1 + (size_t)NBLK * 256;
  float* tmx  = tmn + Bn;
  float* psum = tmx + Bn;
  float* nsum = psum + Bn;

  int n4 = Bn * D / 4;
  convert_kernel<<<(n4 + 255) / 256, 256, 0, stream>>>(feats, fb, n4);

  pair_kernel<1><<<NBLK, 256, 0, stream>>>(fb, labels, nullptr, nullptr, pm0, pm1);
  reduce1_kernel<<<NT, 256, 0, stream>>>(pm0, pm1, tmn, tmx);
  pair_kernel<2><<<NBLK, 256, 0, stream>>>(fb, labels, tmn, tmx, pm0, pm1);
  reduce2_kernel<<<NT, 256, 0, stream>>>(pm0, pm1, psum, nsum);
  finalize_kernel<<<1, 256, 0, stream>>>(psum, nsum, out, Bn);
}